// Round 5
// baseline (217.043 us; speedup 1.0000x reference)
//
#include <hip/hip_runtime.h>

constexpr int C = 128;
#define SCAN_CHUNK 1024   // 256 threads x 4 items per scan block

typedef __attribute__((ext_vector_type(8))) short short8;   // 8 bf16 = 4 VGPR
typedef __attribute__((ext_vector_type(4))) float f32x4;

__device__ __forceinline__ unsigned short f2bf(float f) {   // RNE f32->bf16
  unsigned int u = __float_as_uint(f);
  unsigned int r = (u + 0x7fffu + ((u >> 16) & 1u)) >> 16;
  return (unsigned short)r;
}
__device__ __forceinline__ float bfl(unsigned int p) {  // low bf16 of packed pair
  return __uint_as_float(p << 16);
}
__device__ __forceinline__ float bfh(unsigned int p) {  // high bf16 of packed pair
  return __uint_as_float(p & 0xffff0000u);
}

// ---- phase 0a: W f32 -> bf16 ----
__global__ void k_prep(const float* __restrict__ W, unsigned short* __restrict__ Wb) {
  int i = blockIdx.x * blockDim.x + threadIdx.x;   // 4096 float4 units
  float4 w = ((const float4*)W)[i];
  uint2 pk;
  pk.x = f2bf(w.x) | ((unsigned int)f2bf(w.y) << 16);
  pk.y = f2bf(w.z) | ((unsigned int)f2bf(w.w) << 16);
  ((uint2*)Wb)[i] = pk;
}

// ---- phase 0b: h f32 -> bf16 (halves random-gather bytes) ----
__global__ void k_prep_h(const float* __restrict__ h, unsigned short* __restrict__ hb,
                         int total4) {
  int i = blockIdx.x * blockDim.x + threadIdx.x;   // float4 units
  if (i < total4) {
    float4 w = ((const float4*)h)[i];
    uint2 pk;
    pk.x = f2bf(w.x) | ((unsigned int)f2bf(w.y) << 16);
    pk.y = f2bf(w.z) | ((unsigned int)f2bf(w.w) << 16);
    ((uint2*)hb)[i] = pk;
  }
}

// ---- phase A: degree + d = min(deg^-1/2, 1e4); also zero CSR counts ----
__global__ void k_init(float* __restrict__ deg, int* __restrict__ counts, int n) {
  int i = blockIdx.x * blockDim.x + threadIdx.x;
  if (i < n) { deg[i] = 1.0f; counts[i] = 0; }
}

__global__ void k_edge_deg(const int* __restrict__ dst, const float* __restrict__ ew,
                           float* __restrict__ deg, int* __restrict__ counts, int e) {
  int i = blockIdx.x * blockDim.x + threadIdx.x;
  if (i < e) {
    int t = dst[i];
    unsafeAtomicAdd(&deg[t], ew[i]);
    atomicAdd(&counts[t], 1);
  }
}

__global__ void k_dinv(float* __restrict__ deg, int n) {
  int i = blockIdx.x * blockDim.x + threadIdx.x;
  if (i < n) deg[i] = fminf(1.0f / sqrtf(deg[i]), 10000.0f);
}

// ---- phase B: exclusive scan of counts -> rowptr; cursor = rowptr copy ----
__global__ void k_scan1(const int* __restrict__ cnt, int* __restrict__ excl,
                        int* __restrict__ sums, int n) {
  __shared__ int l[256];
  const int t = threadIdx.x;
  const int base = blockIdx.x * SCAN_CHUNK + t * 4;
  int v0 = 0, v1 = 0, v2 = 0, v3 = 0;
  if (base + 0 < n) v0 = cnt[base + 0];
  if (base + 1 < n) v1 = cnt[base + 1];
  if (base + 2 < n) v2 = cnt[base + 2];
  if (base + 3 < n) v3 = cnt[base + 3];
  const int s = v0 + v1 + v2 + v3;
  l[t] = s; __syncthreads();
  for (int off = 1; off < 256; off <<= 1) {
    int x = 0;
    if (t >= off) x = l[t - off];
    __syncthreads();
    l[t] += x;
    __syncthreads();
  }
  int ex = l[t] - s;
  if (t == 255) sums[blockIdx.x] = l[t];
  if (base + 0 < n) excl[base + 0] = ex;  ex += v0;
  if (base + 1 < n) excl[base + 1] = ex;  ex += v1;
  if (base + 2 < n) excl[base + 2] = ex;  ex += v2;
  if (base + 3 < n) excl[base + 3] = ex;
}

__global__ void k_scan2(int* __restrict__ sums, int nb) {  // nb <= 256
  __shared__ int l[256];
  const int t = threadIdx.x;
  const int s = (t < nb) ? sums[t] : 0;
  l[t] = s; __syncthreads();
  for (int off = 1; off < 256; off <<= 1) {
    int x = 0;
    if (t >= off) x = l[t - off];
    __syncthreads();
    l[t] += x;
    __syncthreads();
  }
  if (t < nb) sums[t] = l[t] - s;
}

__global__ void k_scan3(int* __restrict__ rowptr, const int* __restrict__ sums,
                        int* __restrict__ cursor, int n, int e) {
  int i = blockIdx.x * blockDim.x + threadIdx.x;
  if (i < n) {
    int v = rowptr[i] + sums[i >> 10];
    rowptr[i] = v;
    cursor[i] = v;
  }
  if (i == 0) rowptr[n] = e;
}

// scatter edges into dst-sorted order; norm folded in.
__global__ void k_scatter(const int* __restrict__ src, const int* __restrict__ dst,
                          const float* __restrict__ ew, const float* __restrict__ d,
                          int* __restrict__ cursor, int2* __restrict__ meta, int e) {
  int i = blockIdx.x * blockDim.x + threadIdx.x;
  if (i < e) {
    int t = dst[i], s = src[i];
    float nm = d[s] * ew[i] * d[t];
    int p = atomicAdd(&cursor[t], 1);
    meta[p] = make_int2(s, __float_as_int(nm));
  }
}

// ---- fused: gather-aggregate -> (LDS, bf16) -> MFMA GEMM -> +b +h -> LN -> GELU
// One block = 64 rows. 8 groups x 32 lanes gather 8 nodes each into Al;
// then 4 waves x (16 rows x 128 cols) MFMA. 48 KB LDS -> 3 blocks/CU.
#define TM 64

template <int USE_HB>
__launch_bounds__(256, 3)
__global__ void k_fused(const int* __restrict__ rowptr, const int2* __restrict__ meta,
                        const float* __restrict__ d, const float* __restrict__ h,
                        const unsigned short* __restrict__ hb,
                        const unsigned short* __restrict__ Wb,
                        const float* __restrict__ b,
                        const float* __restrict__ gamma, const float* __restrict__ beta,
                        float* __restrict__ out, int n) {
  __shared__ char lds[48 * 1024];
  char* Wl = lds;              // 32 KB bf16 [128][128], swizzled
  char* Al = lds + 32768;      // 16 KB bf16 [64][128],  swizzled
  const int tid = threadIdx.x;
  const int row0 = blockIdx.x * TM;

  // stage W (bf16, 2048 x 16B units), swizzle: byte ^= (row&7)<<4
  #pragma unroll
  for (int i = 0; i < 8; ++i) {
    int u = tid + i * 256;
    int j = u >> 4, un = u & 15;
    uint4 w = ((const uint4*)Wb)[u];
    *(uint4*)(Wl + j * 256 + ((un * 16) ^ ((j & 7) << 4))) = w;
  }

  // gather: group g = tid>>5 handles rows g*8 .. g*8+7 of the tile
  const int lane32 = tid & 31;
  const int grp = tid >> 5;
  const int cb = lane32 * 4;           // this lane's 4 channels
  for (int t = 0; t < 8; ++t) {
    const int r = grp * 8 + t;
    const int v = row0 + r;
    float4 acc = make_float4(0.f, 0.f, 0.f, 0.f);
    if (v < n) {
      const float dv = d[v];
      const float dd = dv * dv;
      if (USE_HB) {
        uint2 hv = *(const uint2*)(hb + (size_t)v * C + cb);
        acc.x = bfl(hv.x) * dd; acc.y = bfh(hv.x) * dd;
        acc.z = bfl(hv.y) * dd; acc.w = bfh(hv.y) * dd;
      } else {
        float4 hv = *(const float4*)(h + (size_t)v * C + cb);
        acc.x = hv.x * dd; acc.y = hv.y * dd; acc.z = hv.z * dd; acc.w = hv.w * dd;
      }
      int p = rowptr[v];
      const int end = rowptr[v + 1];
      if (USE_HB) {
        for (; p + 4 <= end; p += 4) {
          int2 m0 = meta[p], m1 = meta[p + 1], m2 = meta[p + 2], m3 = meta[p + 3];
          float n0 = __int_as_float(m0.y), n1 = __int_as_float(m1.y);
          float n2 = __int_as_float(m2.y), n3 = __int_as_float(m3.y);
          uint2 x0 = *(const uint2*)(hb + (size_t)m0.x * C + cb);
          uint2 x1 = *(const uint2*)(hb + (size_t)m1.x * C + cb);
          uint2 x2 = *(const uint2*)(hb + (size_t)m2.x * C + cb);
          uint2 x3 = *(const uint2*)(hb + (size_t)m3.x * C + cb);
          acc.x += bfl(x0.x) * n0 + bfl(x1.x) * n1 + bfl(x2.x) * n2 + bfl(x3.x) * n3;
          acc.y += bfh(x0.x) * n0 + bfh(x1.x) * n1 + bfh(x2.x) * n2 + bfh(x3.x) * n3;
          acc.z += bfl(x0.y) * n0 + bfl(x1.y) * n1 + bfl(x2.y) * n2 + bfl(x3.y) * n3;
          acc.w += bfh(x0.y) * n0 + bfh(x1.y) * n1 + bfh(x2.y) * n2 + bfh(x3.y) * n3;
        }
        for (; p < end; ++p) {
          int2 m0 = meta[p];
          float n0 = __int_as_float(m0.y);
          uint2 x0 = *(const uint2*)(hb + (size_t)m0.x * C + cb);
          acc.x += bfl(x0.x) * n0; acc.y += bfh(x0.x) * n0;
          acc.z += bfl(x0.y) * n0; acc.w += bfh(x0.y) * n0;
        }
      } else {
        for (; p + 2 <= end; p += 2) {
          int2 m0 = meta[p], m1 = meta[p + 1];
          float n0 = __int_as_float(m0.y), n1 = __int_as_float(m1.y);
          float4 x0 = *(const float4*)(h + (size_t)m0.x * C + cb);
          float4 x1 = *(const float4*)(h + (size_t)m1.x * C + cb);
          acc.x += x0.x * n0 + x1.x * n1;
          acc.y += x0.y * n0 + x1.y * n1;
          acc.z += x0.z * n0 + x1.z * n1;
          acc.w += x0.w * n0 + x1.w * n1;
        }
        if (p < end) {
          int2 m0 = meta[p];
          float n0 = __int_as_float(m0.y);
          float4 x0 = *(const float4*)(h + (size_t)m0.x * C + cb);
          acc.x += x0.x * n0; acc.y += x0.y * n0; acc.z += x0.z * n0; acc.w += x0.w * n0;
        }
      }
    }
    // write row r (bf16, swizzled): lane's 4 channels -> 8 bytes at cb*2
    uint2 pk;
    pk.x = f2bf(acc.x) | ((unsigned int)f2bf(acc.y) << 16);
    pk.y = f2bf(acc.z) | ((unsigned int)f2bf(acc.w) << 16);
    *(uint2*)(Al + r * 256 + ((cb * 2) ^ ((r & 7) << 4))) = pk;
  }
  __syncthreads();

  // MFMA phase: wave wt owns rows wt*16..+15 of the tile
  const int lane = tid & 63;
  const int wt   = tid >> 6;
  const int c16  = lane & 15;
  const int quad = lane >> 4;

  f32x4 acc[8];
  #pragma unroll
  for (int jt = 0; jt < 8; ++jt) acc[jt] = (f32x4){0.f, 0.f, 0.f, 0.f};

  const int abase = (wt * 16 + c16) * 256;
  const int swz   = (c16 & 7) << 4;
  #pragma unroll
  for (int ks = 0; ks < 4; ++ks) {
    const int koff = ks * 64 + quad * 16;
    short8 af = *(const short8*)(Al + abase + (koff ^ swz));
    #pragma unroll
    for (int jt = 0; jt < 8; ++jt) {
      short8 bf = *(const short8*)(Wl + (jt * 16 + c16) * 256 + (koff ^ swz));
      acc[jt] = __builtin_amdgcn_mfma_f32_16x16x32_bf16(af, bf, acc[jt], 0, 0, 0);
    }
  }

  // epilogue: lane owns rows row0+wt*16+quad*4+i (i=0..3), cols jt*16+c16
  float bj[8], gj[8], btj[8];
  #pragma unroll
  for (int jt = 0; jt < 8; ++jt) {
    int j = jt * 16 + c16;
    bj[jt] = b[j]; gj[jt] = gamma[j]; btj[jt] = beta[j];
  }

  #pragma unroll
  for (int i = 0; i < 4; ++i) {
    const int row = row0 + wt * 16 + quad * 4 + i;
    const bool ok = row < n;
    const float* hrow = h + (size_t)row * C;
    float x[8];
    float s = 0.f, t2 = 0.f;
    #pragma unroll
    for (int jt = 0; jt < 8; ++jt) {
      float v = acc[jt][i] + bj[jt] + (ok ? hrow[jt * 16 + c16] : 0.f);
      x[jt] = v; s += v; t2 += v * v;
    }
    #pragma unroll
    for (int m = 8; m >= 1; m >>= 1) {
      s += __shfl_xor(s, m, 16); t2 += __shfl_xor(t2, m, 16);
    }
    const float inv = 1.0f / C;
    float mean = s * inv;
    float var  = t2 * inv - mean * mean;
    float rstd = rsqrtf(var + 1e-5f);
    if (ok) {
      float* orow = out + (size_t)row * C;
      #pragma unroll
      for (int jt = 0; jt < 8; ++jt) {
        float y = gj[jt] * ((x[jt] - mean) * rstd) + btj[jt];
        orow[jt * 16 + c16] = 0.5f * y * (1.0f + erff(y * 0.70710678118f));
      }
    }
  }
}

extern "C" void kernel_launch(void* const* d_in, const int* in_sizes, int n_in,
                              void* d_out, int out_size, void* d_ws, size_t ws_size,
                              hipStream_t stream) {
  const float* h     = (const float*)d_in[0];
  const int*   ei    = (const int*)d_in[1];
  const float* ew    = (const float*)d_in[2];
  const float* W     = (const float*)d_in[3];
  const float* b     = (const float*)d_in[4];
  const float* gamma = (const float*)d_in[5];
  const float* beta  = (const float*)d_in[6];

  const int n = in_sizes[0] / C;
  const int e = in_sizes[2];
  const int* src = ei;
  const int* dst = ei + e;

  float* out = (float*)d_out;

  // workspace layout
  int2* meta   = (int2*)d_ws;                 // e int2
  float* deg   = (float*)(meta + e);          // n
  int* counts  = (int*)(deg + n);             // n
  int* rowptr  = counts + n;                  // n+1
  int* sums    = rowptr + (n + 1);            // <=256
  int* cursor  = sums + 256;                  // n
  unsigned short* Wb = (unsigned short*)(cursor + n);  // C*C bf16 (32 KB)
  unsigned short* hb = Wb + C * C;            // n*C bf16 (25.6 MB) if it fits

  const size_t need_full = (size_t)((char*)(hb + (size_t)n * C) - (char*)d_ws);
  const int use_hb = (ws_size >= need_full);

  const int nb = (n + SCAN_CHUNK - 1) / SCAN_CHUNK;

  k_prep    <<<C * C / 4 / 256, 256, 0, stream>>>(W, Wb);
  if (use_hb) {
    int total4 = n * C / 4;
    k_prep_h<<<(total4 + 255) / 256, 256, 0, stream>>>(h, hb, total4);
  }
  k_init    <<<(n + 255) / 256, 256, 0, stream>>>(deg, counts, n);
  k_edge_deg<<<(e + 255) / 256, 256, 0, stream>>>(dst, ew, deg, counts, e);
  k_dinv    <<<(n + 255) / 256, 256, 0, stream>>>(deg, n);

  k_scan1   <<<nb, 256, 0, stream>>>(counts, rowptr, sums, n);
  k_scan2   <<<1, 256, 0, stream>>>(sums, nb);
  k_scan3   <<<(n + 255) / 256, 256, 0, stream>>>(rowptr, sums, cursor, n, e);
  k_scatter <<<(e + 255) / 256, 256, 0, stream>>>(src, dst, ew, deg, cursor, meta, e);

  const int grid = (n + TM - 1) / TM;
  if (use_hb)
    k_fused<1><<<grid, 256, 0, stream>>>(rowptr, meta, deg, h, hb, Wb, b, gamma, beta, out, n);
  else
    k_fused<0><<<grid, 256, 0, stream>>>(rowptr, meta, deg, h, hb, Wb, b, gamma, beta, out, n);
}

// Round 6
// 138.294 us; speedup vs baseline: 1.5694x; 1.5694x over previous
//
#include <hip/hip_runtime.h>

constexpr int C = 128;
#define SCAN_CHUNK 1024   // 256 threads x 4 items per scan block

typedef __attribute__((ext_vector_type(8))) short short8;   // 8 bf16 = 4 VGPR
typedef __attribute__((ext_vector_type(4))) float f32x4;

__device__ __forceinline__ unsigned short f2bf(float f) {   // RNE f32->bf16
  unsigned int u = __float_as_uint(f);
  unsigned int r = (u + 0x7fffu + ((u >> 16) & 1u)) >> 16;
  return (unsigned short)r;
}
__device__ __forceinline__ float bfl(unsigned int p) { return __uint_as_float(p << 16); }
__device__ __forceinline__ float bfh(unsigned int p) { return __uint_as_float(p & 0xffff0000u); }

// ---- kA: fused prep: W->bf16, (h->bf16), packed=0 ----
template <int DO_HB>
__global__ void k_prep_all(const float* __restrict__ W, unsigned short* __restrict__ Wb,
                           const float* __restrict__ h, unsigned short* __restrict__ hb,
                           int total4, unsigned long long* __restrict__ packed, int n) {
  const int stride = gridDim.x * blockDim.x;
  const int gid = blockIdx.x * blockDim.x + threadIdx.x;
  for (int i = gid; i < C * C / 4; i += stride) {
    float4 w = ((const float4*)W)[i];
    uint2 pk;
    pk.x = f2bf(w.x) | ((unsigned int)f2bf(w.y) << 16);
    pk.y = f2bf(w.z) | ((unsigned int)f2bf(w.w) << 16);
    ((uint2*)Wb)[i] = pk;
  }
  if (DO_HB) {
    for (int i = gid; i < total4; i += stride) {
      float4 w = ((const float4*)h)[i];
      uint2 pk;
      pk.x = f2bf(w.x) | ((unsigned int)f2bf(w.y) << 16);
      pk.y = f2bf(w.z) | ((unsigned int)f2bf(w.w) << 16);
      ((uint2*)hb)[i] = pk;
    }
  }
  for (int i = gid; i < n; i += stride) packed[i] = 0ull;
}

// ---- kB: one u64 atomic per edge: packed[t] += (1<<40) | fixed32(ew).
// Returned old value gives the CSR slot (old>>40) for free.
__global__ void k_edge_deg(const int* __restrict__ dst, const float* __restrict__ ew,
                           unsigned long long* __restrict__ packed,
                           int* __restrict__ slot, int e) {
  int i = blockIdx.x * blockDim.x + threadIdx.x;
  if (i < e) {
    unsigned long long enc =
        (1ull << 40) | (unsigned long long)(ew[i] * 4294967296.0f);
    unsigned long long old = atomicAdd(&packed[dst[i]], enc);
    slot[i] = (int)(old >> 40);
  }
}

// ---- kC: scan1 over counts (packed>>40) + compute d = min(deg^-1/2,1e4) ----
__global__ void k_scan1(const unsigned long long* __restrict__ packed,
                        float* __restrict__ d, int* __restrict__ excl,
                        int* __restrict__ sums, int n) {
  __shared__ int l[256];
  const int t = threadIdx.x;
  const int base = blockIdx.x * SCAN_CHUNK + t * 4;
  int v0 = 0, v1 = 0, v2 = 0, v3 = 0;
  const float fs = 1.0f / 4294967296.0f;
  const unsigned long long M = (1ull << 40) - 1ull;
  if (base + 0 < n) { unsigned long long p = packed[base + 0]; v0 = (int)(p >> 40);
    d[base + 0] = fminf(1.0f / sqrtf(1.0f + (float)(p & M) * fs), 10000.0f); }
  if (base + 1 < n) { unsigned long long p = packed[base + 1]; v1 = (int)(p >> 40);
    d[base + 1] = fminf(1.0f / sqrtf(1.0f + (float)(p & M) * fs), 10000.0f); }
  if (base + 2 < n) { unsigned long long p = packed[base + 2]; v2 = (int)(p >> 40);
    d[base + 2] = fminf(1.0f / sqrtf(1.0f + (float)(p & M) * fs), 10000.0f); }
  if (base + 3 < n) { unsigned long long p = packed[base + 3]; v3 = (int)(p >> 40);
    d[base + 3] = fminf(1.0f / sqrtf(1.0f + (float)(p & M) * fs), 10000.0f); }
  const int s = v0 + v1 + v2 + v3;
  l[t] = s; __syncthreads();
  for (int off = 1; off < 256; off <<= 1) {
    int x = 0;
    if (t >= off) x = l[t - off];
    __syncthreads();
    l[t] += x;
    __syncthreads();
  }
  int ex = l[t] - s;
  if (t == 255) sums[blockIdx.x] = l[t];
  if (base + 0 < n) excl[base + 0] = ex;  ex += v0;
  if (base + 1 < n) excl[base + 1] = ex;  ex += v1;
  if (base + 2 < n) excl[base + 2] = ex;  ex += v2;
  if (base + 3 < n) excl[base + 3] = ex;
}

__global__ void k_scan2(int* __restrict__ sums, int nb) {  // nb <= 256
  __shared__ int l[256];
  const int t = threadIdx.x;
  const int s = (t < nb) ? sums[t] : 0;
  l[t] = s; __syncthreads();
  for (int off = 1; off < 256; off <<= 1) {
    int x = 0;
    if (t >= off) x = l[t - off];
    __syncthreads();
    l[t] += x;
    __syncthreads();
  }
  if (t < nb) sums[t] = l[t] - s;
}

__global__ void k_scan3(int* __restrict__ rowptr, const int* __restrict__ sums,
                        int n, int e) {
  int i = blockIdx.x * blockDim.x + threadIdx.x;
  if (i < n) rowptr[i] += sums[i >> 10];
  if (i == 0) rowptr[n] = e;
}

// ---- kF: scatter (no atomics): p = rowptr[dst] + slot ----
__global__ void k_scatter(const int* __restrict__ src, const int* __restrict__ dst,
                          const float* __restrict__ ew, const float* __restrict__ d,
                          const int* __restrict__ rowptr, const int* __restrict__ slot,
                          int2* __restrict__ meta, int e) {
  int i = blockIdx.x * blockDim.x + threadIdx.x;
  if (i < e) {
    int t = dst[i], s = src[i];
    float nm = d[s] * ew[i] * d[t];
    int p = rowptr[t] + slot[i];
    meta[p] = make_int2(s, __float_as_int(nm));
  }
}

// ---- kG: gather-aggregate, 32 lanes per dst node, unroll-4 ----
template <int USE_HB, int OUT_BF>
__global__ void k_gather(const int* __restrict__ rowptr, const int2* __restrict__ meta,
                         const float* __restrict__ d, const float* __restrict__ h,
                         const unsigned short* __restrict__ hb,
                         float* __restrict__ aggf, unsigned short* __restrict__ aggb,
                         int n) {
  int g = blockIdx.x * blockDim.x + threadIdx.x;
  int v = g >> 5, lane = g & 31;
  if (v >= n) return;
  const int cb = lane * 4;
  const float dv = d[v];
  const float dd = dv * dv;
  float4 acc;
  if (USE_HB) {
    uint2 hv = *(const uint2*)(hb + (size_t)v * C + cb);
    acc = make_float4(bfl(hv.x) * dd, bfh(hv.x) * dd, bfl(hv.y) * dd, bfh(hv.y) * dd);
  } else {
    float4 hv = *(const float4*)(h + (size_t)v * C + cb);
    acc = make_float4(hv.x * dd, hv.y * dd, hv.z * dd, hv.w * dd);
  }
  int p = rowptr[v];
  const int end = rowptr[v + 1];
  if (USE_HB) {
    for (; p + 4 <= end; p += 4) {
      int2 m0 = meta[p], m1 = meta[p + 1], m2 = meta[p + 2], m3 = meta[p + 3];
      float n0 = __int_as_float(m0.y), n1 = __int_as_float(m1.y);
      float n2 = __int_as_float(m2.y), n3 = __int_as_float(m3.y);
      uint2 x0 = *(const uint2*)(hb + (size_t)m0.x * C + cb);
      uint2 x1 = *(const uint2*)(hb + (size_t)m1.x * C + cb);
      uint2 x2 = *(const uint2*)(hb + (size_t)m2.x * C + cb);
      uint2 x3 = *(const uint2*)(hb + (size_t)m3.x * C + cb);
      acc.x += bfl(x0.x) * n0 + bfl(x1.x) * n1 + bfl(x2.x) * n2 + bfl(x3.x) * n3;
      acc.y += bfh(x0.x) * n0 + bfh(x1.x) * n1 + bfh(x2.x) * n2 + bfh(x3.x) * n3;
      acc.z += bfl(x0.y) * n0 + bfl(x1.y) * n1 + bfl(x2.y) * n2 + bfl(x3.y) * n3;
      acc.w += bfh(x0.y) * n0 + bfh(x1.y) * n1 + bfh(x2.y) * n2 + bfh(x3.y) * n3;
    }
    for (; p < end; ++p) {
      int2 m0 = meta[p];
      float n0 = __int_as_float(m0.y);
      uint2 x0 = *(const uint2*)(hb + (size_t)m0.x * C + cb);
      acc.x += bfl(x0.x) * n0; acc.y += bfh(x0.x) * n0;
      acc.z += bfl(x0.y) * n0; acc.w += bfh(x0.y) * n0;
    }
  } else {
    for (; p + 4 <= end; p += 4) {
      int2 m0 = meta[p], m1 = meta[p + 1], m2 = meta[p + 2], m3 = meta[p + 3];
      float n0 = __int_as_float(m0.y), n1 = __int_as_float(m1.y);
      float n2 = __int_as_float(m2.y), n3 = __int_as_float(m3.y);
      float4 x0 = *(const float4*)(h + (size_t)m0.x * C + cb);
      float4 x1 = *(const float4*)(h + (size_t)m1.x * C + cb);
      float4 x2 = *(const float4*)(h + (size_t)m2.x * C + cb);
      float4 x3 = *(const float4*)(h + (size_t)m3.x * C + cb);
      acc.x += x0.x * n0 + x1.x * n1 + x2.x * n2 + x3.x * n3;
      acc.y += x0.y * n0 + x1.y * n1 + x2.y * n2 + x3.y * n3;
      acc.z += x0.z * n0 + x1.z * n1 + x2.z * n2 + x3.z * n3;
      acc.w += x0.w * n0 + x1.w * n1 + x2.w * n2 + x3.w * n3;
    }
    for (; p < end; ++p) {
      int2 m0 = meta[p];
      float n0 = __int_as_float(m0.y);
      float4 x0 = *(const float4*)(h + (size_t)m0.x * C + cb);
      acc.x += x0.x * n0; acc.y += x0.y * n0; acc.z += x0.z * n0; acc.w += x0.w * n0;
    }
  }
  if (OUT_BF) {
    uint2 pk;
    pk.x = f2bf(acc.x) | ((unsigned int)f2bf(acc.y) << 16);
    pk.y = f2bf(acc.z) | ((unsigned int)f2bf(acc.w) << 16);
    *(uint2*)(aggb + (size_t)v * C + cb) = pk;
  } else {
    *(float4*)(aggf + (size_t)v * C + cb) = acc;
  }
}

// ---- kH: x = agg @ W^T + b + h ; LN ; exact GELU  (bf16 MFMA) ----
#define TM 64

template <int IN_BF>
__launch_bounds__(256, 3)
__global__ void k_mfma_ln_gelu(const float* __restrict__ aggf,
                               const unsigned short* __restrict__ aggb,
                               const float* __restrict__ h,
                               const unsigned short* __restrict__ Wb,
                               const float* __restrict__ b,
                               const float* __restrict__ gamma, const float* __restrict__ beta,
                               float* __restrict__ out, int n) {
  __shared__ char lds[48 * 1024];
  char* Wl = lds;              // 32 KB bf16 [128][128], swizzled
  char* Al = lds + 32768;      // 16 KB bf16 [64][128],  swizzled
  const int tid = threadIdx.x;
  const int row0 = blockIdx.x * TM;

  // stage W (bf16, 2048 x 16B units), swizzle: byte ^= (row&7)<<4
  #pragma unroll
  for (int i = 0; i < 8; ++i) {
    int u = tid + i * 256;
    int j = u >> 4, un = u & 15;
    uint4 w = ((const uint4*)Wb)[u];
    *(uint4*)(Wl + j * 256 + ((un * 16) ^ ((j & 7) << 4))) = w;
  }
  // stage A tile (2048 8B units: row = u>>5, unit = u&31)
  #pragma unroll
  for (int i = 0; i < 8; ++i) {
    int u = tid + i * 256;
    int j = u >> 5;
    int rr = row0 + j; if (rr >= n) rr = n - 1;
    uint2 pk;
    if (IN_BF) {
      pk = ((const uint2*)(aggb + (size_t)rr * C))[u & 31];
    } else {
      float4 a = ((const float4*)(aggf + (size_t)rr * C))[u & 31];
      pk.x = f2bf(a.x) | ((unsigned int)f2bf(a.y) << 16);
      pk.y = f2bf(a.z) | ((unsigned int)f2bf(a.w) << 16);
    }
    *(uint2*)(Al + j * 256 + (((u & 31) * 8) ^ ((j & 7) << 4))) = pk;
  }
  __syncthreads();

  const int lane = tid & 63;
  const int wt   = tid >> 6;
  const int c16  = lane & 15;
  const int quad = lane >> 4;

  f32x4 acc[8];
  #pragma unroll
  for (int jt = 0; jt < 8; ++jt) acc[jt] = (f32x4){0.f, 0.f, 0.f, 0.f};

  const int abase = (wt * 16 + c16) * 256;
  const int swz   = (c16 & 7) << 4;
  #pragma unroll
  for (int ks = 0; ks < 4; ++ks) {
    const int koff = ks * 64 + quad * 16;
    short8 af = *(const short8*)(Al + abase + (koff ^ swz));
    #pragma unroll
    for (int jt = 0; jt < 8; ++jt) {
      short8 bf = *(const short8*)(Wl + (jt * 16 + c16) * 256 + (koff ^ swz));
      acc[jt] = __builtin_amdgcn_mfma_f32_16x16x32_bf16(af, bf, acc[jt], 0, 0, 0);
    }
  }

  float bj[8], gj[8], btj[8];
  #pragma unroll
  for (int jt = 0; jt < 8; ++jt) {
    int j = jt * 16 + c16;
    bj[jt] = b[j]; gj[jt] = gamma[j]; btj[jt] = beta[j];
  }

  #pragma unroll
  for (int i = 0; i < 4; ++i) {
    const int row = row0 + wt * 16 + quad * 4 + i;
    const bool ok = row < n;
    const float* hrow = h + (size_t)row * C;
    float x[8];
    float s = 0.f, t2 = 0.f;
    #pragma unroll
    for (int jt = 0; jt < 8; ++jt) {
      float v = acc[jt][i] + bj[jt] + (ok ? hrow[jt * 16 + c16] : 0.f);
      x[jt] = v; s += v; t2 += v * v;
    }
    #pragma unroll
    for (int m = 8; m >= 1; m >>= 1) {
      s += __shfl_xor(s, m, 16); t2 += __shfl_xor(t2, m, 16);
    }
    const float inv = 1.0f / C;
    float mean = s * inv;
    float var  = t2 * inv - mean * mean;
    float rstd = rsqrtf(var + 1e-5f);
    if (ok) {
      float* orow = out + (size_t)row * C;
      #pragma unroll
      for (int jt = 0; jt < 8; ++jt) {
        float y = gj[jt] * ((x[jt] - mean) * rstd) + btj[jt];
        orow[jt * 16 + c16] = 0.5f * y * (1.0f + erff(y * 0.70710678118f));
      }
    }
  }
}

extern "C" void kernel_launch(void* const* d_in, const int* in_sizes, int n_in,
                              void* d_out, int out_size, void* d_ws, size_t ws_size,
                              hipStream_t stream) {
  const float* h     = (const float*)d_in[0];
  const int*   ei    = (const int*)d_in[1];
  const float* ew    = (const float*)d_in[2];
  const float* W     = (const float*)d_in[3];
  const float* b     = (const float*)d_in[4];
  const float* gamma = (const float*)d_in[5];
  const float* beta  = (const float*)d_in[6];

  const int n = in_sizes[0] / C;
  const int e = in_sizes[2];
  const int* src = ei;
  const int* dst = ei + e;

  float* out = (float*)d_out;

  // workspace layout
  int2* meta    = (int2*)d_ws;                          // e
  unsigned long long* packed = (unsigned long long*)(meta + e);  // n (8B aligned)
  int* slot     = (int*)(packed + n);                   // e
  float* d      = (float*)(slot + e);                   // n
  int* rowptr   = (int*)(d + n);                        // n+1
  int* sums     = rowptr + (n + 1);                     // <=256
  unsigned short* Wb = (unsigned short*)(sums + 256);   // C*C
  unsigned short* hb = Wb + C * C;                      // n*C
  unsigned short* aggb = hb + (size_t)n * C;            // n*C

  const size_t need_mid  = (size_t)((char*)(hb + (size_t)n * C) - (char*)d_ws);
  const size_t need_full = (size_t)((char*)(aggb + (size_t)n * C) - (char*)d_ws);
  const int mode = (ws_size >= need_full) ? 2 : (ws_size >= need_mid) ? 1 : 0;

  const int nb = (n + SCAN_CHUNK - 1) / SCAN_CHUNK;
  const int total4 = n * C / 4;

  if (mode >= 1)
    k_prep_all<1><<<1024, 256, 0, stream>>>(W, Wb, h, hb, total4, packed, n);
  else
    k_prep_all<0><<<1024, 256, 0, stream>>>(W, Wb, h, hb, total4, packed, n);

  k_edge_deg<<<(e + 255) / 256, 256, 0, stream>>>(dst, ew, packed, slot, e);
  k_scan1   <<<nb, 256, 0, stream>>>(packed, d, rowptr, sums, n);
  k_scan2   <<<1, 256, 0, stream>>>(sums, nb);
  k_scan3   <<<(n + 255) / 256, 256, 0, stream>>>(rowptr, sums, n, e);
  k_scatter <<<(e + 255) / 256, 256, 0, stream>>>(src, dst, ew, d, rowptr, slot, meta, e);

  const long gthreads = (long)n * 32;
  const int ggrid = (int)((gthreads + 255) / 256);
  const int mgrid = (n + TM - 1) / TM;

  if (mode == 2) {
    k_gather<1, 1><<<ggrid, 256, 0, stream>>>(rowptr, meta, d, h, hb, out, aggb, n);
    k_mfma_ln_gelu<1><<<mgrid, 256, 0, stream>>>(out, aggb, h, Wb, b, gamma, beta, out, n);
  } else if (mode == 1) {
    k_gather<1, 0><<<ggrid, 256, 0, stream>>>(rowptr, meta, d, h, hb, out, aggb, n);
    k_mfma_ln_gelu<0><<<mgrid, 256, 0, stream>>>(out, aggb, h, Wb, b, gamma, beta, out, n);
  } else {
    k_gather<0, 0><<<ggrid, 256, 0, stream>>>(rowptr, meta, d, h, hb, out, aggb, n);
    k_mfma_ln_gelu<0><<<mgrid, 256, 0, stream>>>(out, aggb, h, Wb, b, gamma, beta, out, n);
  }
}